// Round 1
// baseline (4533.849 us; speedup 1.0000x reference)
//
#include <hip/hip_runtime.h>

// GraphSAGE 2-layer, fp32. N=100000, F_IN=64, H=128, E=1.6M.
// Strategy: aggregate-then-GEMM (linearity). Edge aggregation via HW f32
// atomics (unsafeAtomicAdd -> global_atomic_add_f32). Dense layers on vector
// ALU (no fp32 MFMA on CDNA4) with LDS-staged transposed weights.

// ---------------- edge aggregation ----------------
// One thread per (edge, 4-feature chunk). Consecutive threads cover one
// feature row contiguously -> coalesced float4 gather of x[src].
template<int F, bool DO_CNT>
__global__ __launch_bounds__(256) void agg_edges_kernel(
    const int* __restrict__ ei,      // [2, E]: src = ei[0:E], dst = ei[E:2E]
    const float* __restrict__ feat,  // [N, F]
    float* __restrict__ agg,         // [N, F] (pre-zeroed)
    float* __restrict__ cnt,         // [N]    (pre-zeroed)
    int E)
{
    constexpr int Q = F / 4;
    int idx = blockIdx.x * 256 + threadIdx.x;
    if (idx >= E * Q) return;
    int e = idx / Q;          // power-of-2 -> shifts
    int q = idx - e * Q;
    int s = ei[e];
    int d = ei[E + e];
    const float4 v = *reinterpret_cast<const float4*>(&feat[(size_t)s * F + q * 4]);
    float* dp = &agg[(size_t)d * F + q * 4];
    unsafeAtomicAdd(dp + 0, v.x);
    unsafeAtomicAdd(dp + 1, v.y);
    unsafeAtomicAdd(dp + 2, v.z);
    unsafeAtomicAdd(dp + 3, v.w);
    if (DO_CNT && q == 0) unsafeAtomicAdd(&cnt[d], 1.0f);
}

// ---------------- dense layer ----------------
// out[n][j] = sum_k (agg[n][k]/max(cnt,1))*Wl[j][k] + bl[j] + x[n][k]*Wr[j][k]
// Block = 256 thr = 8 rgroups of 32 lanes. Lane owns 4 consecutive j.
// rgroup owns R=8 rows -> 64 rows/block. Weights staged transposed in LDS
// (wlT[kk][j]) so the float4 read along j is wave-contiguous (conflict-free).
// Row data read as wave-uniform broadcast float4 loads from global (L1/L2).
template<int F, bool RELU>
__global__ __launch_bounds__(256) void dense_kernel(
    const float* __restrict__ agg,
    const float* __restrict__ cnt,
    const float* __restrict__ xroot,
    const float* __restrict__ Wl,    // [128, F]
    const float* __restrict__ bl,    // [128]
    const float* __restrict__ Wr,    // [128, F]
    float* __restrict__ out,         // [N, 128]
    int N)
{
    constexpr int KP = 32;   // k per LDS phase
    constexpr int R  = 8;    // rows per rgroup
    __shared__ float wlT[KP][128];
    __shared__ float wrT[KP][128];

    const int tid    = threadIdx.x;
    const int lane32 = tid & 31;
    const int rg     = tid >> 5;          // 0..7
    const int j0     = lane32 * 4;        // output col base
    const int rowBase = blockIdx.x * (8 * R) + rg * R;

    float acc[R][4];
    #pragma unroll
    for (int r = 0; r < R; ++r)
        acc[r][0] = acc[r][1] = acc[r][2] = acc[r][3] = 0.f;

    int   rows[R];
    float inv[R];
    #pragma unroll
    for (int r = 0; r < R; ++r) {
        int row = rowBase + r;
        bool ok = row < N;
        rows[r] = ok ? row : 0;           // clamp so loads stay in-bounds
        float c = ok ? cnt[row] : 1.f;
        inv[r] = 1.0f / fmaxf(c, 1.0f);
    }

    for (int p = 0; p < F; p += KP) {
        __syncthreads();
        // stage transposed weights: wlT[kk][j] = Wl[j][p+kk]
        for (int t = tid; t < KP * 32; t += 256) {
            int kk = t >> 5;
            int j4 = (t & 31) * 4;
            int gk = p + kk;
            float4 vl, vr;
            vl.x = Wl[(j4 + 0) * F + gk];
            vl.y = Wl[(j4 + 1) * F + gk];
            vl.z = Wl[(j4 + 2) * F + gk];
            vl.w = Wl[(j4 + 3) * F + gk];
            vr.x = Wr[(j4 + 0) * F + gk];
            vr.y = Wr[(j4 + 1) * F + gk];
            vr.z = Wr[(j4 + 2) * F + gk];
            vr.w = Wr[(j4 + 3) * F + gk];
            *reinterpret_cast<float4*>(&wlT[kk][j4]) = vl;
            *reinterpret_cast<float4*>(&wrT[kk][j4]) = vr;
        }
        __syncthreads();

        #pragma unroll 2
        for (int kk4 = 0; kk4 < KP; kk4 += 4) {
            float4 wl4[4], wr4[4];
            #pragma unroll
            for (int c = 0; c < 4; ++c) {
                wl4[c] = *reinterpret_cast<const float4*>(&wlT[kk4 + c][j0]);
                wr4[c] = *reinterpret_cast<const float4*>(&wrT[kk4 + c][j0]);
            }
            #pragma unroll
            for (int r = 0; r < R; ++r) {
                const size_t base = (size_t)rows[r] * F + p + kk4;
                float4 m4 = *reinterpret_cast<const float4*>(&agg[base]);
                float4 x4 = *reinterpret_cast<const float4*>(&xroot[base]);
                m4.x *= inv[r]; m4.y *= inv[r]; m4.z *= inv[r]; m4.w *= inv[r];
                #pragma unroll
                for (int c = 0; c < 4; ++c) {
                    float mv = (&m4.x)[c];
                    float xv = (&x4.x)[c];
                    acc[r][0] = fmaf(mv, wl4[c].x, acc[r][0]);
                    acc[r][0] = fmaf(xv, wr4[c].x, acc[r][0]);
                    acc[r][1] = fmaf(mv, wl4[c].y, acc[r][1]);
                    acc[r][1] = fmaf(xv, wr4[c].y, acc[r][1]);
                    acc[r][2] = fmaf(mv, wl4[c].z, acc[r][2]);
                    acc[r][2] = fmaf(xv, wr4[c].z, acc[r][2]);
                    acc[r][3] = fmaf(mv, wl4[c].w, acc[r][3]);
                    acc[r][3] = fmaf(xv, wr4[c].w, acc[r][3]);
                }
            }
        }
    }

    const float4 b4 = *reinterpret_cast<const float4*>(&bl[j0]);
    #pragma unroll
    for (int r = 0; r < R; ++r) {
        int row = rowBase + r;
        if (row < N) {
            float4 o;
            o.x = acc[r][0] + b4.x;
            o.y = acc[r][1] + b4.y;
            o.z = acc[r][2] + b4.z;
            o.w = acc[r][3] + b4.w;
            if (RELU) {
                o.x = fmaxf(o.x, 0.f);
                o.y = fmaxf(o.y, 0.f);
                o.z = fmaxf(o.z, 0.f);
                o.w = fmaxf(o.w, 0.f);
            }
            *reinterpret_cast<float4*>(&out[(size_t)row * 128 + j0]) = o;
        }
    }
}

extern "C" void kernel_launch(void* const* d_in, const int* in_sizes, int n_in,
                              void* d_out, int out_size, void* d_ws, size_t ws_size,
                              hipStream_t stream) {
    const float* x   = (const float*)d_in[0];
    const int*   ei  = (const int*)d_in[1];
    const float* Wl1 = (const float*)d_in[2];
    const float* bl1 = (const float*)d_in[3];
    const float* Wr1 = (const float*)d_in[4];
    const float* Wl2 = (const float*)d_in[5];
    const float* bl2 = (const float*)d_in[6];
    const float* Wr2 = (const float*)d_in[7];
    float* out = (float*)d_out;

    const int N = in_sizes[0] / 64;   // 100000
    const int E = in_sizes[1] / 2;    // 1600000

    // ws layout (floats): agg1[N*64] | cnt[N] | h[N*128] | agg2[N*128]
    float* ws   = (float*)d_ws;
    float* agg1 = ws;
    float* cnt  = agg1 + (size_t)N * 64;
    float* h    = cnt + N;
    float* agg2 = h + (size_t)N * 128;

    // zero the accumulation buffers (ws is poisoned 0xAA before every call)
    hipMemsetAsync(agg1, 0, ((size_t)N * 64 + N) * sizeof(float), stream);
    hipMemsetAsync(agg2, 0, (size_t)N * 128 * sizeof(float), stream);

    {   // layer-1 aggregation + degree count
        int total = E * 16;
        agg_edges_kernel<64, true><<<(total + 255) / 256, 256, 0, stream>>>(
            ei, x, agg1, cnt, E);
    }
    {   // layer-1 dense + relu -> h
        dense_kernel<64, true><<<(N + 63) / 64, 256, 0, stream>>>(
            agg1, cnt, x, Wl1, bl1, Wr1, h, N);
    }
    {   // layer-2 aggregation
        int total = E * 32;
        agg_edges_kernel<128, false><<<(total + 255) / 256, 256, 0, stream>>>(
            ei, h, agg2, nullptr, E);
    }
    {   // layer-2 dense -> out
        dense_kernel<128, false><<<(N + 63) / 64, 256, 0, stream>>>(
            agg2, cnt, h, Wl2, bl2, Wr2, out, N);
    }
}

// Round 2
// 859.740 us; speedup vs baseline: 5.2735x; 5.2735x over previous
//
#include <hip/hip_runtime.h>

// GraphSAGE 2-layer, fp32. N=100000, F_IN=64, H=128, E=1.6M.
// Round 2: replace scatter-atomic aggregation (3.2 GB atomic writeback, 3.9ms)
// with device-built CSR (hist -> scan -> scatter) + gather aggregation.
// Gathers hit L3 (x=25.6MB, h=51.2MB); agg writes are coalesced, no atomics.

// ---------------- CSR build ----------------
__global__ __launch_bounds__(256) void hist_kernel(
    const int* __restrict__ ei, int* __restrict__ deg, int E)
{
    int e = blockIdx.x * 256 + threadIdx.x;
    if (e < E) atomicAdd(&deg[ei[E + e]], 1);
}

// phase A: per-block (1024-elem chunk) sums
__global__ __launch_bounds__(256) void scan_reduce_kernel(
    const int* __restrict__ deg, int* __restrict__ bsum, int N)
{
    int base = blockIdx.x * 1024;
    int s = 0;
    for (int i = threadIdx.x; i < 1024; i += 256) {
        int g = base + i;
        if (g < N) s += deg[g];
    }
    __shared__ int sh[256];
    sh[threadIdx.x] = s;
    __syncthreads();
    for (int o = 128; o > 0; o >>= 1) {
        if (threadIdx.x < o) sh[threadIdx.x] += sh[threadIdx.x + o];
        __syncthreads();
    }
    if (threadIdx.x == 0) bsum[blockIdx.x] = sh[0];
}

// phase B: single-block exclusive scan of block sums (nb <= 128)
__global__ __launch_bounds__(128) void scan_bsum_kernel(
    int* __restrict__ bsum, int nb, int* __restrict__ totalOut)
{
    __shared__ int sh[128];
    int t = threadIdx.x;
    int v = (t < nb) ? bsum[t] : 0;
    sh[t] = v;
    __syncthreads();
    for (int o = 1; o < 128; o <<= 1) {
        int a = (t >= o) ? sh[t - o] : 0;
        __syncthreads();
        sh[t] += a;
        __syncthreads();
    }
    if (t < nb) bsum[t] = sh[t] - v;            // exclusive prefix
    if (t == 127) *totalOut = sh[127];          // total edge count -> rowptr[N]
}

// phase C: per-chunk exclusive scan + add block offset -> rowptr, cursor
// NOTE: cursor may alias deg — each index is read (deg) then written (cursor)
// by exactly one thread, no cross-thread access to the same index.
__global__ __launch_bounds__(256) void scan_apply_kernel(
    const int* __restrict__ deg, const int* __restrict__ bsum,
    int* __restrict__ rowptr, int* __restrict__ cursor, int N)
{
    int t = threadIdx.x;
    int g0 = blockIdx.x * 1024 + t * 4;
    int d0 = (g0 + 0 < N) ? deg[g0 + 0] : 0;
    int d1 = (g0 + 1 < N) ? deg[g0 + 1] : 0;
    int d2 = (g0 + 2 < N) ? deg[g0 + 2] : 0;
    int d3 = (g0 + 3 < N) ? deg[g0 + 3] : 0;
    int ts = d0 + d1 + d2 + d3;
    __shared__ int sh[256];
    sh[t] = ts;
    __syncthreads();
    for (int o = 1; o < 256; o <<= 1) {
        int a = (t >= o) ? sh[t - o] : 0;
        __syncthreads();
        sh[t] += a;
        __syncthreads();
    }
    int p0 = sh[t] - ts + bsum[blockIdx.x];
    int p1 = p0 + d0, p2 = p1 + d1, p3 = p2 + d2;
    if (g0 + 0 < N) { rowptr[g0 + 0] = p0; cursor[g0 + 0] = p0; }
    if (g0 + 1 < N) { rowptr[g0 + 1] = p1; cursor[g0 + 1] = p1; }
    if (g0 + 2 < N) { rowptr[g0 + 2] = p2; cursor[g0 + 2] = p2; }
    if (g0 + 3 < N) { rowptr[g0 + 3] = p3; cursor[g0 + 3] = p3; }
}

__global__ __launch_bounds__(256) void scatter_kernel(
    const int* __restrict__ ei, int* __restrict__ cursor,
    int* __restrict__ ssrc, int E)
{
    int e = blockIdx.x * 256 + threadIdx.x;
    if (e < E) {
        int d = ei[E + e];
        int p = atomicAdd(&cursor[d], 1);
        ssrc[p] = ei[e];
    }
}

// ---------------- gather aggregation ----------------
// One wave per dst node. Lane<->feature mapping: F=64 -> 1 float/lane,
// F=128 -> float2/lane. Edge src indices loaded once per 64 edges, then
// broadcast via __shfl; each edge = one coalesced 256B/512B row gather.
template<int F>
__global__ __launch_bounds__(256) void agg_gather_kernel(
    const int* __restrict__ rowptr, const int* __restrict__ ssrc,
    const float* __restrict__ feat, float* __restrict__ agg, int N)
{
    constexpr int V = F / 64;   // floats per lane
    int wave = threadIdx.x >> 6;
    int lane = threadIdx.x & 63;
    int n = blockIdx.x * 4 + wave;
    if (n >= N) return;
    int rp = rowptr[n], re = rowptr[n + 1];
    float acc0 = 0.f, acc1 = 0.f;
    for (int jb = rp; jb < re; jb += 64) {
        int cnt = min(64, re - jb);
        int myidx = (lane < cnt) ? ssrc[jb + lane] : 0;
        int t = 0;
        for (; t + 4 <= cnt; t += 4) {
            int s0 = __shfl(myidx, t + 0);
            int s1 = __shfl(myidx, t + 1);
            int s2 = __shfl(myidx, t + 2);
            int s3 = __shfl(myidx, t + 3);
            if constexpr (V == 1) {
                float v0 = feat[(size_t)s0 * F + lane];
                float v1 = feat[(size_t)s1 * F + lane];
                float v2 = feat[(size_t)s2 * F + lane];
                float v3 = feat[(size_t)s3 * F + lane];
                acc0 += v0 + v1 + v2 + v3;
            } else {
                float2 v0 = *reinterpret_cast<const float2*>(&feat[(size_t)s0 * F + lane * 2]);
                float2 v1 = *reinterpret_cast<const float2*>(&feat[(size_t)s1 * F + lane * 2]);
                float2 v2 = *reinterpret_cast<const float2*>(&feat[(size_t)s2 * F + lane * 2]);
                float2 v3 = *reinterpret_cast<const float2*>(&feat[(size_t)s3 * F + lane * 2]);
                acc0 += v0.x + v1.x + v2.x + v3.x;
                acc1 += v0.y + v1.y + v2.y + v3.y;
            }
        }
        for (; t < cnt; ++t) {
            int s = __shfl(myidx, t);
            if constexpr (V == 1) {
                acc0 += feat[(size_t)s * F + lane];
            } else {
                float2 v = *reinterpret_cast<const float2*>(&feat[(size_t)s * F + lane * 2]);
                acc0 += v.x; acc1 += v.y;
            }
        }
    }
    if constexpr (V == 1) {
        agg[(size_t)n * F + lane] = acc0;
    } else {
        *reinterpret_cast<float2*>(&agg[(size_t)n * F + lane * 2]) = make_float2(acc0, acc1);
    }
}

// ---------------- dense layer ----------------
// out[n][j] = (agg[n][:]/max(deg,1)) . Wl[j][:] + bl[j] + x[n][:] . Wr[j][:]
// degree derived from rowptr. Structure unchanged from round 1.
template<int F, bool RELU>
__global__ __launch_bounds__(256) void dense_kernel(
    const float* __restrict__ agg,
    const int* __restrict__ rowptr,
    const float* __restrict__ xroot,
    const float* __restrict__ Wl,    // [128, F]
    const float* __restrict__ bl,    // [128]
    const float* __restrict__ Wr,    // [128, F]
    float* __restrict__ out,         // [N, 128]
    int N)
{
    constexpr int KP = 32;
    constexpr int R  = 8;
    __shared__ float wlT[KP][128];
    __shared__ float wrT[KP][128];

    const int tid    = threadIdx.x;
    const int lane32 = tid & 31;
    const int rg     = tid >> 5;
    const int j0     = lane32 * 4;
    const int rowBase = blockIdx.x * (8 * R) + rg * R;

    float acc[R][4];
    #pragma unroll
    for (int r = 0; r < R; ++r)
        acc[r][0] = acc[r][1] = acc[r][2] = acc[r][3] = 0.f;

    int   rows[R];
    float inv[R];
    #pragma unroll
    for (int r = 0; r < R; ++r) {
        int row = rowBase + r;
        bool ok = row < N;
        rows[r] = ok ? row : 0;
        int dgr = ok ? (rowptr[row + 1] - rowptr[row]) : 1;
        inv[r] = 1.0f / (float)max(dgr, 1);
    }

    for (int p = 0; p < F; p += KP) {
        __syncthreads();
        for (int t = tid; t < KP * 32; t += 256) {
            int kk = t >> 5;
            int j4 = (t & 31) * 4;
            int gk = p + kk;
            float4 vl, vr;
            vl.x = Wl[(j4 + 0) * F + gk];
            vl.y = Wl[(j4 + 1) * F + gk];
            vl.z = Wl[(j4 + 2) * F + gk];
            vl.w = Wl[(j4 + 3) * F + gk];
            vr.x = Wr[(j4 + 0) * F + gk];
            vr.y = Wr[(j4 + 1) * F + gk];
            vr.z = Wr[(j4 + 2) * F + gk];
            vr.w = Wr[(j4 + 3) * F + gk];
            *reinterpret_cast<float4*>(&wlT[kk][j4]) = vl;
            *reinterpret_cast<float4*>(&wrT[kk][j4]) = vr;
        }
        __syncthreads();

        #pragma unroll 2
        for (int kk4 = 0; kk4 < KP; kk4 += 4) {
            float4 wl4[4], wr4[4];
            #pragma unroll
            for (int c = 0; c < 4; ++c) {
                wl4[c] = *reinterpret_cast<const float4*>(&wlT[kk4 + c][j0]);
                wr4[c] = *reinterpret_cast<const float4*>(&wrT[kk4 + c][j0]);
            }
            #pragma unroll
            for (int r = 0; r < R; ++r) {
                const size_t base = (size_t)rows[r] * F + p + kk4;
                float4 m4 = *reinterpret_cast<const float4*>(&agg[base]);
                float4 x4 = *reinterpret_cast<const float4*>(&xroot[base]);
                m4.x *= inv[r]; m4.y *= inv[r]; m4.z *= inv[r]; m4.w *= inv[r];
                #pragma unroll
                for (int c = 0; c < 4; ++c) {
                    float mv = (&m4.x)[c];
                    float xv = (&x4.x)[c];
                    acc[r][0] = fmaf(mv, wl4[c].x, acc[r][0]);
                    acc[r][0] = fmaf(xv, wr4[c].x, acc[r][0]);
                    acc[r][1] = fmaf(mv, wl4[c].y, acc[r][1]);
                    acc[r][1] = fmaf(xv, wr4[c].y, acc[r][1]);
                    acc[r][2] = fmaf(mv, wl4[c].z, acc[r][2]);
                    acc[r][2] = fmaf(xv, wr4[c].z, acc[r][2]);
                    acc[r][3] = fmaf(mv, wl4[c].w, acc[r][3]);
                    acc[r][3] = fmaf(xv, wr4[c].w, acc[r][3]);
                }
            }
        }
    }

    const float4 b4 = *reinterpret_cast<const float4*>(&bl[j0]);
    #pragma unroll
    for (int r = 0; r < R; ++r) {
        int row = rowBase + r;
        if (row < N) {
            float4 o;
            o.x = acc[r][0] + b4.x;
            o.y = acc[r][1] + b4.y;
            o.z = acc[r][2] + b4.z;
            o.w = acc[r][3] + b4.w;
            if (RELU) {
                o.x = fmaxf(o.x, 0.f);
                o.y = fmaxf(o.y, 0.f);
                o.z = fmaxf(o.z, 0.f);
                o.w = fmaxf(o.w, 0.f);
            }
            *reinterpret_cast<float4*>(&out[(size_t)row * 128 + j0]) = o;
        }
    }
}

extern "C" void kernel_launch(void* const* d_in, const int* in_sizes, int n_in,
                              void* d_out, int out_size, void* d_ws, size_t ws_size,
                              hipStream_t stream) {
    const float* x   = (const float*)d_in[0];
    const int*   ei  = (const int*)d_in[1];
    const float* Wl1 = (const float*)d_in[2];
    const float* bl1 = (const float*)d_in[3];
    const float* Wr1 = (const float*)d_in[4];
    const float* Wl2 = (const float*)d_in[5];
    const float* bl2 = (const float*)d_in[6];
    const float* Wr2 = (const float*)d_in[7];
    float* out = (float*)d_out;

    const int N = in_sizes[0] / 64;   // 100000
    const int E = in_sizes[1] / 2;    // 1600000
    const int nb = (N + 1023) / 1024; // scan chunks (98)

    // ws layout (ints then floats), ~110 MB total:
    //   ssrc[E] | rowptr[N+1] | deg[N] (aliased as cursor) | bsum[128] | aggbuf[N*128] | h[N*128]
    int* ssrc   = (int*)d_ws;
    int* rowptr = ssrc + E;
    int* deg    = rowptr + (N + 1);
    int* cursor = deg;                 // alias — deg is dead after scan_apply
    int* bsum   = deg + N;
    size_t intCount = (size_t)E + (N + 1) + N + 128;
    intCount = (intCount + 3) & ~(size_t)3;          // 16B align
    float* aggbuf = (float*)(ssrc + intCount);       // reused by both layers
    float* h      = aggbuf + (size_t)N * 128;

    // CSR build (deg zero-init; ws is re-poisoned 0xAA before every call)
    hipMemsetAsync(deg, 0, (size_t)N * sizeof(int), stream);
    hist_kernel<<<(E + 255) / 256, 256, 0, stream>>>(ei, deg, E);
    scan_reduce_kernel<<<nb, 256, 0, stream>>>(deg, bsum, N);
    scan_bsum_kernel<<<1, 128, 0, stream>>>(bsum, nb, &rowptr[N]);
    scan_apply_kernel<<<nb, 256, 0, stream>>>(deg, bsum, rowptr, cursor, N);
    scatter_kernel<<<(E + 255) / 256, 256, 0, stream>>>(ei, cursor, ssrc, E);

    // layer 1: gather-agg + dense(+relu)
    agg_gather_kernel<64><<<(N + 3) / 4, 256, 0, stream>>>(rowptr, ssrc, x, aggbuf, N);
    dense_kernel<64, true><<<(N + 63) / 64, 256, 0, stream>>>(
        aggbuf, rowptr, x, Wl1, bl1, Wr1, h, N);

    // layer 2: gather-agg + dense
    agg_gather_kernel<128><<<(N + 3) / 4, 256, 0, stream>>>(rowptr, ssrc, h, aggbuf, N);
    dense_kernel<128, false><<<(N + 63) / 64, 256, 0, stream>>>(
        aggbuf, rowptr, h, Wl2, bl2, Wr2, out, N);
}

// Round 3
// 584.320 us; speedup vs baseline: 7.7592x; 1.4714x over previous
//
#include <hip/hip_runtime.h>

// GraphSAGE 2-layer, fp32. N=100000, F_IN=64, H=128, E=1.6M.
// Round 3: dense layers moved to bf16 MFMA with split-precision (hi+lo bf16,
// 3 MFMA passes: a0w0 + a0w1 + a1w0; rel err ~2^-16). Weights pre-split into
// fragment-ordered global arrays (coalesced 16B/lane loads, no LDS). A operands
// (mean / x / h) stay fp32 in memory, split on the fly in-register.
// CSR build + gather aggregation unchanged from round 2.

typedef __attribute__((ext_vector_type(8))) short bf16x8;  // MFMA A/B frag
typedef __attribute__((ext_vector_type(4))) float f32x4;   // MFMA C/D frag

union ABu { unsigned u[4]; bf16x8 v; };

// split 8 fp32 -> hi (bf16 trunc) + lo (bf16 of exact residual)
__device__ inline void splitA(const f32x4 fA, const f32x4 fB,
                              bf16x8& hi, bf16x8& lo) {
    ABu H, L;
    float f[8] = {fA.x, fA.y, fA.z, fA.w, fB.x, fB.y, fB.z, fB.w};
    #pragma unroll
    for (int p = 0; p < 4; ++p) {
        unsigned u0 = __float_as_uint(f[2*p]);
        unsigned u1 = __float_as_uint(f[2*p+1]);
        unsigned h0 = u0 & 0xFFFF0000u;
        unsigned h1 = u1 & 0xFFFF0000u;
        H.u[p] = (u0 >> 16) | h1;
        float r0 = f[2*p]   - __uint_as_float(h0);
        float r1 = f[2*p+1] - __uint_as_float(h1);
        L.u[p] = (__float_as_uint(r0) >> 16) | (__float_as_uint(r1) & 0xFFFF0000u);
    }
    hi = H.v; lo = L.v;
}

// ---------------- CSR build ----------------
__global__ __launch_bounds__(256) void hist_kernel(
    const int* __restrict__ ei, int* __restrict__ deg, int E)
{
    int e = blockIdx.x * 256 + threadIdx.x;
    if (e < E) atomicAdd(&deg[ei[E + e]], 1);
}

__global__ __launch_bounds__(256) void scan_reduce_kernel(
    const int* __restrict__ deg, int* __restrict__ bsum, int N)
{
    int base = blockIdx.x * 1024;
    int s = 0;
    for (int i = threadIdx.x; i < 1024; i += 256) {
        int g = base + i;
        if (g < N) s += deg[g];
    }
    __shared__ int sh[256];
    sh[threadIdx.x] = s;
    __syncthreads();
    for (int o = 128; o > 0; o >>= 1) {
        if (threadIdx.x < o) sh[threadIdx.x] += sh[threadIdx.x + o];
        __syncthreads();
    }
    if (threadIdx.x == 0) bsum[blockIdx.x] = sh[0];
}

__global__ __launch_bounds__(128) void scan_bsum_kernel(
    int* __restrict__ bsum, int nb, int* __restrict__ totalOut)
{
    __shared__ int sh[128];
    int t = threadIdx.x;
    int v = (t < nb) ? bsum[t] : 0;
    sh[t] = v;
    __syncthreads();
    for (int o = 1; o < 128; o <<= 1) {
        int a = (t >= o) ? sh[t - o] : 0;
        __syncthreads();
        sh[t] += a;
        __syncthreads();
    }
    if (t < nb) bsum[t] = sh[t] - v;
    if (t == 127) *totalOut = sh[127];
}

__global__ __launch_bounds__(256) void scan_apply_kernel(
    const int* __restrict__ deg, const int* __restrict__ bsum,
    int* __restrict__ rowptr, int* __restrict__ cursor, int N)
{
    int t = threadIdx.x;
    int g0 = blockIdx.x * 1024 + t * 4;
    int d0 = (g0 + 0 < N) ? deg[g0 + 0] : 0;
    int d1 = (g0 + 1 < N) ? deg[g0 + 1] : 0;
    int d2 = (g0 + 2 < N) ? deg[g0 + 2] : 0;
    int d3 = (g0 + 3 < N) ? deg[g0 + 3] : 0;
    int ts = d0 + d1 + d2 + d3;
    __shared__ int sh[256];
    sh[t] = ts;
    __syncthreads();
    for (int o = 1; o < 256; o <<= 1) {
        int a = (t >= o) ? sh[t - o] : 0;
        __syncthreads();
        sh[t] += a;
        __syncthreads();
    }
    int p0 = sh[t] - ts + bsum[blockIdx.x];
    int p1 = p0 + d0, p2 = p1 + d1, p3 = p2 + d2;
    if (g0 + 0 < N) { rowptr[g0 + 0] = p0; cursor[g0 + 0] = p0; }
    if (g0 + 1 < N) { rowptr[g0 + 1] = p1; cursor[g0 + 1] = p1; }
    if (g0 + 2 < N) { rowptr[g0 + 2] = p2; cursor[g0 + 2] = p2; }
    if (g0 + 3 < N) { rowptr[g0 + 3] = p3; cursor[g0 + 3] = p3; }
}

__global__ __launch_bounds__(256) void scatter_kernel(
    const int* __restrict__ ei, int* __restrict__ cursor,
    int* __restrict__ ssrc, int E)
{
    int e = blockIdx.x * 256 + threadIdx.x;
    if (e < E) {
        int d = ei[E + e];
        int p = atomicAdd(&cursor[d], 1);
        ssrc[p] = ei[e];
    }
}

// ---------------- weight prep: split + fragment-order ----------------
// Wcat[k][j] = (k<F ? Wl[j][k] : Wr[j][k-F]), K=2F, j in [0,128).
// Frag order: for frag fr = ks*8 + j, lane l, elem e:
//   k = ks*32 + (l>>4)*8 + e, col = j*16 + (l&15)
//   w{0,1}f[(fr*64 + l)*8 + e]
__global__ __launch_bounds__(256) void prep_w_kernel(
    const float* __restrict__ Wl, const float* __restrict__ Wr, int F,
    short* __restrict__ w0f, short* __restrict__ w1f, int nfrag)
{
    int t = blockIdx.x * 256 + threadIdx.x;   // one thread per (frag, lane)
    if (t >= nfrag * 64) return;
    int lane = t & 63, fr = t >> 6;
    int j  = fr & 7, ks = fr >> 3;
    int col = j * 16 + (lane & 15);
    int k0  = ks * 32 + (lane >> 4) * 8;
    #pragma unroll
    for (int e = 0; e < 8; ++e) {
        int k = k0 + e;
        float w = (k < F) ? Wl[col * F + k] : Wr[col * F + (k - F)];
        unsigned u = __float_as_uint(w);
        unsigned h = u & 0xFFFF0000u;
        float r = w - __uint_as_float(h);
        w0f[t * 8 + e] = (short)(u >> 16);
        w1f[t * 8 + e] = (short)(__float_as_uint(r) >> 16);
    }
}

// ---------------- gather aggregation (writes scaled mean) ----------------
template<int F>
__global__ __launch_bounds__(256) void agg_gather_kernel(
    const int* __restrict__ rowptr, const int* __restrict__ ssrc,
    const float* __restrict__ feat, float* __restrict__ mean, int N)
{
    constexpr int V = F / 64;
    int wave = threadIdx.x >> 6;
    int lane = threadIdx.x & 63;
    int n = blockIdx.x * 4 + wave;
    if (n >= N) return;
    int rp = rowptr[n], re = rowptr[n + 1];
    float acc0 = 0.f, acc1 = 0.f;
    for (int jb = rp; jb < re; jb += 64) {
        int cnt = min(64, re - jb);
        int myidx = (lane < cnt) ? ssrc[jb + lane] : 0;
        int t = 0;
        for (; t + 4 <= cnt; t += 4) {
            int s0 = __shfl(myidx, t + 0);
            int s1 = __shfl(myidx, t + 1);
            int s2 = __shfl(myidx, t + 2);
            int s3 = __shfl(myidx, t + 3);
            if constexpr (V == 1) {
                acc0 += feat[(size_t)s0 * F + lane] + feat[(size_t)s1 * F + lane]
                      + feat[(size_t)s2 * F + lane] + feat[(size_t)s3 * F + lane];
            } else {
                float2 v0 = *reinterpret_cast<const float2*>(&feat[(size_t)s0 * F + lane * 2]);
                float2 v1 = *reinterpret_cast<const float2*>(&feat[(size_t)s1 * F + lane * 2]);
                float2 v2 = *reinterpret_cast<const float2*>(&feat[(size_t)s2 * F + lane * 2]);
                float2 v3 = *reinterpret_cast<const float2*>(&feat[(size_t)s3 * F + lane * 2]);
                acc0 += v0.x + v1.x + v2.x + v3.x;
                acc1 += v0.y + v1.y + v2.y + v3.y;
            }
        }
        for (; t < cnt; ++t) {
            int s = __shfl(myidx, t);
            if constexpr (V == 1) {
                acc0 += feat[(size_t)s * F + lane];
            } else {
                float2 v = *reinterpret_cast<const float2*>(&feat[(size_t)s * F + lane * 2]);
                acc0 += v.x; acc1 += v.y;
            }
        }
    }
    float inv = 1.0f / (float)max(re - rp, 1);
    if constexpr (V == 1) {
        mean[(size_t)n * F + lane] = acc0 * inv;
    } else {
        *reinterpret_cast<float2*>(&mean[(size_t)n * F + lane * 2]) =
            make_float2(acc0 * inv, acc1 * inv);
    }
}

// ---------------- dense layer via split-bf16 MFMA ----------------
// out[M=N x 128] = [left | right] (fp32, split on the fly) @ Wfrag + bl
// Wave: 32 rows x 128 cols = 2 rowtiles x 8 jtiles of 16x16 frags.
// Block: 4 waves = 128 rows. No LDS; B-frags are fragment-ordered global.
template<int F, bool RELU>
__global__ __launch_bounds__(256, 2) void dense_mfma_kernel(
    const float* __restrict__ left,    // mean [N][F]
    const float* __restrict__ right,   // x or h [N][F]
    const short* __restrict__ w0f,     // [(2F/32)*8][64][8]
    const short* __restrict__ w1f,
    const float* __restrict__ bl,      // [128]
    float* __restrict__ out,           // [N][128]
    int N)
{
    constexpr int NS = (2 * F) / 32;   // k-steps
    const int tid  = threadIdx.x;
    const int lane = tid & 63;
    const int wv   = tid >> 6;
    const int r16  = lane & 15;
    const int kg   = lane >> 4;        // 0..3: k-group of 8
    const int rowBase = blockIdx.x * 128 + wv * 32;

    const int row0 = min(rowBase + r16,      N - 1);
    const int row1 = min(rowBase + 16 + r16, N - 1);

    f32x4 acc[2][8];
    #pragma unroll
    for (int rt = 0; rt < 2; ++rt)
        #pragma unroll
        for (int j = 0; j < 8; ++j)
            acc[rt][j] = (f32x4){0.f, 0.f, 0.f, 0.f};

    #pragma unroll
    for (int ks = 0; ks < NS; ++ks) {
        const bool Lh = (ks * 32) < F;                // uniform per ks (unrolled)
        const float* __restrict__ src = Lh ? left : right;
        const int koff = ks * 32 - (Lh ? 0 : F) + kg * 8;

        bf16x8 a0[2], a1[2];
        {
            const float* ap0 = src + (size_t)row0 * F + koff;
            splitA(*reinterpret_cast<const f32x4*>(ap0),
                   *reinterpret_cast<const f32x4*>(ap0 + 4), a0[0], a1[0]);
            const float* ap1 = src + (size_t)row1 * F + koff;
            splitA(*reinterpret_cast<const f32x4*>(ap1),
                   *reinterpret_cast<const f32x4*>(ap1 + 4), a0[1], a1[1]);
        }

        #pragma unroll
        for (int j = 0; j < 8; ++j) {
            const size_t fb = (((size_t)(ks * 8 + j)) * 64 + lane) * 8;
            const bf16x8 b0 = *reinterpret_cast<const bf16x8*>(&w0f[fb]);
            const bf16x8 b1 = *reinterpret_cast<const bf16x8*>(&w1f[fb]);
            #pragma unroll
            for (int rt = 0; rt < 2; ++rt) {
                acc[rt][j] = __builtin_amdgcn_mfma_f32_16x16x32_bf16(
                    a0[rt], b0, acc[rt][j], 0, 0, 0);
                acc[rt][j] = __builtin_amdgcn_mfma_f32_16x16x32_bf16(
                    a0[rt], b1, acc[rt][j], 0, 0, 0);
                acc[rt][j] = __builtin_amdgcn_mfma_f32_16x16x32_bf16(
                    a1[rt], b0, acc[rt][j], 0, 0, 0);
            }
        }
    }

    // epilogue: C/D layout col = lane&15, row = (lane>>4)*4 + i
    #pragma unroll
    for (int j = 0; j < 8; ++j) {
        const int col = j * 16 + r16;
        const float b = bl[col];
        #pragma unroll
        for (int rt = 0; rt < 2; ++rt) {
            const int rb = rowBase + rt * 16 + kg * 4;
            #pragma unroll
            for (int i = 0; i < 4; ++i) {
                int row = rb + i;
                if (row < N) {
                    float v = acc[rt][j][i] + b;
                    if (RELU) v = fmaxf(v, 0.f);
                    out[(size_t)row * 128 + col] = v;
                }
            }
        }
    }
}

extern "C" void kernel_launch(void* const* d_in, const int* in_sizes, int n_in,
                              void* d_out, int out_size, void* d_ws, size_t ws_size,
                              hipStream_t stream) {
    const float* x   = (const float*)d_in[0];
    const int*   ei  = (const int*)d_in[1];
    const float* Wl1 = (const float*)d_in[2];
    const float* bl1 = (const float*)d_in[3];
    const float* Wr1 = (const float*)d_in[4];
    const float* Wl2 = (const float*)d_in[5];
    const float* bl2 = (const float*)d_in[6];
    const float* Wr2 = (const float*)d_in[7];
    float* out = (float*)d_out;

    const int N = in_sizes[0] / 64;   // 100000
    const int E = in_sizes[1] / 2;    // 1600000
    const int nb = (N + 1023) / 1024; // scan chunks (98)

    // ws layout: ints | short weight frags | floats
    int* ssrc   = (int*)d_ws;
    int* rowptr = ssrc + E;
    int* deg    = rowptr + (N + 1);
    int* cursor = deg;                // alias — deg dead after scan_apply
    int* bsum   = deg + N;
    short* w0f1 = (short*)(bsum + 128);       // 32 frags * 512
    short* w1f1 = w0f1 + 32 * 512;
    short* w0f2 = w1f1 + 32 * 512;            // 64 frags * 512
    short* w1f2 = w0f2 + 64 * 512;
    size_t shortEnd = (size_t)(w1f2 + 64 * 512 - (short*)d_ws);
    size_t floatOff = (shortEnd * 2 + 15) / 16 * 4;   // 16B-aligned float index
    float* meanbuf = (float*)d_ws + floatOff;          // [N][128] (layer1 uses F=64)
    float* h       = meanbuf + (size_t)N * 128;        // [N][128]

    // CSR build
    hipMemsetAsync(deg, 0, (size_t)N * sizeof(int), stream);
    hist_kernel<<<(E + 255) / 256, 256, 0, stream>>>(ei, deg, E);
    scan_reduce_kernel<<<nb, 256, 0, stream>>>(deg, bsum, N);
    scan_bsum_kernel<<<1, 128, 0, stream>>>(bsum, nb, &rowptr[N]);
    scan_apply_kernel<<<nb, 256, 0, stream>>>(deg, bsum, rowptr, cursor, N);
    scatter_kernel<<<(E + 255) / 256, 256, 0, stream>>>(ei, cursor, ssrc, E);

    // weight prep (fragment-ordered split-bf16)
    prep_w_kernel<<<(32 * 64 + 255) / 256, 256, 0, stream>>>(Wl1, Wr1, 64, w0f1, w1f1, 32);
    prep_w_kernel<<<(64 * 64 + 255) / 256, 256, 0, stream>>>(Wl2, Wr2, 128, w0f2, w1f2, 64);

    const int dgrid = (N + 127) / 128;

    // layer 1
    agg_gather_kernel<64><<<(N + 3) / 4, 256, 0, stream>>>(rowptr, ssrc, x, meanbuf, N);
    dense_mfma_kernel<64, true><<<dgrid, 256, 0, stream>>>(
        meanbuf, x, w0f1, w1f1, bl1, h, N);

    // layer 2
    agg_gather_kernel<128><<<(N + 3) / 4, 256, 0, stream>>>(rowptr, ssrc, h, meanbuf, N);
    dense_mfma_kernel<128, false><<<dgrid, 256, 0, stream>>>(
        meanbuf, h, w0f2, w1f2, bl2, out, N);
}